// Round 1
// baseline (1267.297 us; speedup 1.0000x reference)
//
#include <hip/hip_runtime.h>

#define N_NODES 20000
#define N_EDGES 400000
#define BATCH   4096

// ---- order-preserving float<->uint encoding for atomicMax on signed floats
__device__ __forceinline__ unsigned enc_f(float f) {
    unsigned u = __float_as_uint(f);
    return (u & 0x80000000u) ? ~u : (u | 0x80000000u);
}
__device__ __forceinline__ float dec_f(unsigned e) {
    return (e & 0x80000000u) ? __uint_as_float(e & 0x7fffffffu)
                             : __uint_as_float(~e);
}

// ---- xl = x@Wl, xr = x@Wr  (x: [N][K], W: [K][128], out: [N][128])
// 16 nodes per block, 128 threads (one output column each).
template<int K>
__global__ __launch_bounds__(128)
void transform_kernel(const float* __restrict__ x,
                      const float* __restrict__ Wl,
                      const float* __restrict__ Wr,
                      float* __restrict__ xl,
                      float* __restrict__ xr)
{
    __shared__ float xs[16 * K];
    const int t  = threadIdx.x;      // output column 0..127
    const int n0 = blockIdx.x * 16;
    for (int idx = t; idx < 16 * K; idx += 128)
        xs[idx] = x[(size_t)n0 * K + idx];
    __syncthreads();

    float accl[16], accr[16];
#pragma unroll
    for (int g = 0; g < 16; ++g) { accl[g] = 0.f; accr[g] = 0.f; }

    for (int k = 0; k < K; ++k) {
        const float wl = Wl[k * 128 + t];
        const float wr = Wr[k * 128 + t];
#pragma unroll
        for (int g = 0; g < 16; ++g) {
            const float xv = xs[g * K + k];
            accl[g] = fmaf(xv, wl, accl[g]);
            accr[g] = fmaf(xv, wr, accr[g]);
        }
    }
#pragma unroll
    for (int g = 0; g < 16; ++g) {
        xl[(size_t)(n0 + g) * 128 + t] = accl[g];
        xr[(size_t)(n0 + g) * 128 + t] = accr[g];
    }
}

// ---- per-edge GATv2 score: e[h] = sum_d lrelu(xl[src,h,d]+xr[dst,h,d])*a[h,d]
// one wave (64 lanes) per edge; lane d covers dim d (head0) and d+64 (head1)
__global__ __launch_bounds__(256)
void score_kernel(const float* __restrict__ xl, const float* __restrict__ xr,
                  const int* __restrict__ src, const int* __restrict__ dst,
                  const float* __restrict__ a,
                  float* __restrict__ esc, unsigned* __restrict__ menc, int E)
{
    const int wid  = (int)((blockIdx.x * blockDim.x + threadIdx.x) >> 6);
    const int lane = threadIdx.x & 63;
    if (wid >= E) return;
    const int s = src[wid], d = dst[wid];
    const float* xls = xl + (size_t)s * 128;
    const float* xrd = xr + (size_t)d * 128;

    float v0 = xls[lane]      + xrd[lane];
    float v1 = xls[lane + 64] + xrd[lane + 64];
    v0 = v0 >= 0.f ? v0 : 0.2f * v0;
    v1 = v1 >= 0.f ? v1 : 0.2f * v1;
    float p0 = v0 * a[lane];
    float p1 = v1 * a[lane + 64];
#pragma unroll
    for (int off = 32; off > 0; off >>= 1) {
        p0 += __shfl_xor(p0, off, 64);
        p1 += __shfl_xor(p1, off, 64);
    }
    if (lane == 0) {
        esc[2 * wid]     = p0;
        esc[2 * wid + 1] = p1;
        atomicMax(&menc[2 * d],     enc_f(p0));
        atomicMax(&menc[2 * d + 1], enc_f(p1));
    }
}

// ---- ex = exp(e - m[dst]); s[dst] += ex   (thread per edge*head)
__global__ __launch_bounds__(256)
void expsum_kernel(const int* __restrict__ dst, float* __restrict__ esc,
                   const unsigned* __restrict__ menc, float* __restrict__ ssum,
                   int E)
{
    const int t = blockIdx.x * blockDim.x + threadIdx.x;
    if (t >= 2 * E) return;
    const int e = t >> 1, h = t & 1;
    const int d = dst[e];
    const float m  = dec_f(menc[2 * d + h]);
    const float ex = expf(esc[t] - m);
    esc[t] = ex;
    atomicAdd(&ssum[2 * d + h], ex);
}

// ---- agg[dst] += (ex/(s[dst]+1e-16) * ew) * xl[src]   (wave per edge)
__global__ __launch_bounds__(256)
void agg_kernel(const float* __restrict__ xl,
                const int* __restrict__ src, const int* __restrict__ dst,
                const float* __restrict__ ew,
                const float* __restrict__ esc, const float* __restrict__ ssum,
                float* __restrict__ agg, int E)
{
    const int wid  = (int)((blockIdx.x * blockDim.x + threadIdx.x) >> 6);
    const int lane = threadIdx.x & 63;
    if (wid >= E) return;
    const int s = src[wid], d = dst[wid];
    const float w  = ew[wid];
    const float c0 = esc[2 * wid]     / (ssum[2 * d]     + 1e-16f) * w;
    const float c1 = esc[2 * wid + 1] / (ssum[2 * d + 1] + 1e-16f) * w;
    const float* xls = xl + (size_t)s * 128;
    float* ad = agg + (size_t)d * 128;
    atomicAdd(&ad[lane],      c0 * xls[lane]);
    atomicAdd(&ad[lane + 64], c1 * xls[lane + 64]);
}

// ---- layers 0..2: x = elu(agg + b)  (concat layout already [N][128])
__global__ __launch_bounds__(256)
void finalize_kernel(const float* __restrict__ agg, const float* __restrict__ b,
                     float* __restrict__ xout, int total)
{
    const int t = blockIdx.x * blockDim.x + threadIdx.x;
    if (t >= total) return;
    const float v = agg[t] + b[t & 127];
    xout[t] = v > 0.f ? v : expm1f(v);
}

// ---- layer 3: x = mean over heads + b  ([N][64]), no activation
__global__ __launch_bounds__(256)
void finalize3_kernel(const float* __restrict__ agg, const float* __restrict__ b,
                      float* __restrict__ xout)
{
    const int t = blockIdx.x * blockDim.x + threadIdx.x;
    if (t >= N_NODES * 64) return;
    const int n = t >> 6, j = t & 63;
    xout[t] = 0.5f * (agg[n * 128 + j] + agg[n * 128 + 64 + j]) + b[j];
}

// ---- out[i] = x[pert_indices[i]]   ([B][64])
__global__ __launch_bounds__(256)
void gather_kernel(const float* __restrict__ x, const int* __restrict__ idx,
                   float* __restrict__ out)
{
    const int t = blockIdx.x * blockDim.x + threadIdx.x;
    if (t >= BATCH * 64) return;
    const int i = t >> 6, j = t & 63;
    out[t] = x[(size_t)idx[i] * 64 + j];
}

extern "C" void kernel_launch(void* const* d_in, const int* in_sizes, int n_in,
                              void* d_out, int out_size, void* d_ws, size_t ws_size,
                              hipStream_t stream)
{
    const int*   pert = (const int*)d_in[0];
    const int*   eidx = (const int*)d_in[1];
    const float* ew   = (const float*)d_in[2];
    const float* emb  = (const float*)d_in[3];
    const float* Wl[4] = {(const float*)d_in[4],  (const float*)d_in[8],
                          (const float*)d_in[12], (const float*)d_in[16]};
    const float* Wr[4] = {(const float*)d_in[5],  (const float*)d_in[9],
                          (const float*)d_in[13], (const float*)d_in[17]};
    const float* av[4] = {(const float*)d_in[6],  (const float*)d_in[10],
                          (const float*)d_in[14], (const float*)d_in[18]};
    const float* bv[4] = {(const float*)d_in[7],  (const float*)d_in[11],
                          (const float*)d_in[15], (const float*)d_in[19]};

    const int N = N_NODES, E = N_EDGES;
    const int* srcp = eidx;
    const int* dstp = eidx + E;

    // workspace layout (floats)
    float*    ws   = (float*)d_ws;
    float*    xbuf = ws;                          // N*128
    float*    xl   = xbuf + (size_t)N * 128;      // N*128
    float*    xr   = xl   + (size_t)N * 128;      // N*128
    float*    esc  = xr   + (size_t)N * 128;      // E*2
    unsigned* menc = (unsigned*)(esc + (size_t)E * 2); // N*2
    float*    ssum = (float*)menc + (size_t)N * 2;     // N*2
    float*    agg  = ssum + (size_t)N * 2;             // N*128
    // total ~44.5 MB

    const float* x = emb;
    for (int layer = 0; layer < 4; ++layer) {
        // zero menc + ssum + agg in one shot (contiguous)
        hipMemsetAsync(menc, 0, ((size_t)N * 2 + (size_t)N * 2 + (size_t)N * 128) * 4,
                       stream);
        if (layer == 0)
            transform_kernel<64><<<N / 16, 128, 0, stream>>>(x, Wl[layer], Wr[layer], xl, xr);
        else
            transform_kernel<128><<<N / 16, 128, 0, stream>>>(x, Wl[layer], Wr[layer], xl, xr);

        score_kernel<<<(E + 3) / 4, 256, 0, stream>>>(xl, xr, srcp, dstp, av[layer],
                                                      esc, menc, E);
        expsum_kernel<<<(2 * E + 255) / 256, 256, 0, stream>>>(dstp, esc, menc, ssum, E);
        agg_kernel<<<(E + 3) / 4, 256, 0, stream>>>(xl, srcp, dstp, ew, esc, ssum, agg, E);

        if (layer < 3)
            finalize_kernel<<<(N * 128 + 255) / 256, 256, 0, stream>>>(agg, bv[layer],
                                                                        xbuf, N * 128);
        else
            finalize3_kernel<<<(N * 64 + 255) / 256, 256, 0, stream>>>(agg, bv[3], xbuf);
        x = xbuf;
    }

    gather_kernel<<<(BATCH * 64 + 255) / 256, 256, 0, stream>>>(xbuf, pert, (float*)d_out);
}

// Round 2
// 536.100 us; speedup vs baseline: 2.3639x; 2.3639x over previous
//
#include <hip/hip_runtime.h>
#include <math.h>

#define N_NODES 20000
#define N_EDGES 400000
#define BATCH   4096

// ---- xl = x@Wl, xr = x@Wr  (x: [N][K], W: [K][128], out: [N][128])
// 16 nodes per block, 128 threads (one output column each).
template<int K>
__global__ __launch_bounds__(128)
void transform_kernel(const float* __restrict__ x,
                      const float* __restrict__ Wl,
                      const float* __restrict__ Wr,
                      float* __restrict__ xl,
                      float* __restrict__ xr)
{
    __shared__ float xs[16 * K];
    const int t  = threadIdx.x;      // output column 0..127
    const int n0 = blockIdx.x * 16;
    for (int idx = t; idx < 16 * K; idx += 128)
        xs[idx] = x[(size_t)n0 * K + idx];
    __syncthreads();

    float accl[16], accr[16];
#pragma unroll
    for (int g = 0; g < 16; ++g) { accl[g] = 0.f; accr[g] = 0.f; }

    for (int k = 0; k < K; ++k) {
        const float wl = Wl[k * 128 + t];
        const float wr = Wr[k * 128 + t];
#pragma unroll
        for (int g = 0; g < 16; ++g) {
            const float xv = xs[g * K + k];
            accl[g] = fmaf(xv, wl, accl[g]);
            accr[g] = fmaf(xv, wr, accr[g]);
        }
    }
#pragma unroll
    for (int g = 0; g < 16; ++g) {
        xl[(size_t)(n0 + g) * 128 + t] = accl[g];
        xr[(size_t)(n0 + g) * 128 + t] = accr[g];
    }
}

// ---- CSR build: count degrees
__global__ __launch_bounds__(256)
void count_deg_kernel(const int* __restrict__ dst, int* __restrict__ deg, int E)
{
    const int e = blockIdx.x * blockDim.x + threadIdx.x;
    if (e < E) atomicAdd(&deg[dst[e]], 1);
}

// ---- exclusive scan over 20000 degrees; one block of 1024 threads
#define CHUNK 20
__global__ __launch_bounds__(1024)
void scan_kernel(const int* __restrict__ deg, int* __restrict__ off,
                 int* __restrict__ cursor)
{
    __shared__ int sums[1024];
    const int t = threadIdx.x;
    const int base = t * CHUNK;
    int local[CHUNK];
    int s = 0;
#pragma unroll
    for (int i = 0; i < CHUNK; ++i) {
        const int idx = base + i;
        local[i] = s;
        s += (idx < N_NODES) ? deg[idx] : 0;
    }
    sums[t] = s;
    __syncthreads();
    // Hillis-Steele inclusive scan over 1024 partials
    for (int d = 1; d < 1024; d <<= 1) {
        int v = (t >= d) ? sums[t - d] : 0;
        __syncthreads();
        sums[t] += v;
        __syncthreads();
    }
    const int prev = (t == 0) ? 0 : sums[t - 1];
#pragma unroll
    for (int i = 0; i < CHUNK; ++i) {
        const int idx = base + i;
        if (idx < N_NODES) {
            const int o = prev + local[i];
            off[idx] = o;
            cursor[idx] = o;
        } else if (idx == N_NODES) {
            off[N_NODES] = prev + local[i];
        }
    }
}

// ---- scatter edges into dst-sorted order
__global__ __launch_bounds__(256)
void scatter_kernel(const int* __restrict__ src, const int* __restrict__ dst,
                    const float* __restrict__ ew, int* __restrict__ cursor,
                    int* __restrict__ ssrc, float* __restrict__ sew, int E)
{
    const int e = blockIdx.x * blockDim.x + threadIdx.x;
    if (e >= E) return;
    const int p = atomicAdd(&cursor[dst[e]], 1);
    ssrc[p] = src[e];
    sew[p]  = ew[e];
}

// ---- fused GATv2 layer: one wave per dst node, online softmax in registers.
// lane d covers dim d (head0) and d+64 (head1).
template<int LAST>
__global__ __launch_bounds__(256)
void gat_node_kernel(const float* __restrict__ xl, const float* __restrict__ xr,
                     const int* __restrict__ off, const int* __restrict__ ssrc,
                     const float* __restrict__ sew, const float* __restrict__ a,
                     const float* __restrict__ b, float* __restrict__ xout)
{
    const int node = (int)((blockIdx.x * blockDim.x + threadIdx.x) >> 6);
    const int lane = threadIdx.x & 63;
    if (node >= N_NODES) return;

    const float* xrd = xr + (size_t)node * 128;
    const float xr0 = xrd[lane];
    const float xr1 = xrd[lane + 64];
    const float a0  = a[lane];
    const float a1  = a[lane + 64];

    const int e0 = off[node], e1 = off[node + 1];

    float m0 = -INFINITY, m1 = -INFINITY;
    float s0 = 0.f, s1 = 0.f;
    float acc0 = 0.f, acc1 = 0.f;

    for (int e = e0; e < e1; ++e) {
        const int   sn = ssrc[e];
        const float w  = sew[e];
        const float* xls = xl + (size_t)sn * 128;
        const float x0 = xls[lane];
        const float x1 = xls[lane + 64];

        float v0 = x0 + xr0;
        float v1 = x1 + xr1;
        v0 = v0 >= 0.f ? v0 : 0.2f * v0;
        v1 = v1 >= 0.f ? v1 : 0.2f * v1;
        float p0 = v0 * a0;
        float p1 = v1 * a1;
#pragma unroll
        for (int o = 32; o > 0; o >>= 1) {
            p0 += __shfl_xor(p0, o, 64);
            p1 += __shfl_xor(p1, o, 64);
        }
        // online softmax update, head 0
        {
            const float nm = fmaxf(m0, p0);
            const float r  = expf(m0 - nm);   // 0 when m0 == -inf
            const float ex = expf(p0 - nm);
            s0   = s0 * r + ex;
            acc0 = acc0 * r + ex * w * x0;
            m0 = nm;
        }
        // head 1
        {
            const float nm = fmaxf(m1, p1);
            const float r  = expf(m1 - nm);
            const float ex = expf(p1 - nm);
            s1   = s1 * r + ex;
            acc1 = acc1 * r + ex * w * x1;
            m1 = nm;
        }
    }

    const float o0 = acc0 / (s0 + 1e-16f);
    const float o1 = acc1 / (s1 + 1e-16f);

    if (!LAST) {
        float u0 = o0 + b[lane];
        float u1 = o1 + b[lane + 64];
        u0 = u0 > 0.f ? u0 : expm1f(u0);
        u1 = u1 > 0.f ? u1 : expm1f(u1);
        xout[(size_t)node * 128 + lane]      = u0;
        xout[(size_t)node * 128 + lane + 64] = u1;
    } else {
        xout[(size_t)node * 64 + lane] = 0.5f * (o0 + o1) + b[lane];
    }
}

// ---- out[i] = x[pert_indices[i]]   ([B][64])
__global__ __launch_bounds__(256)
void gather_kernel(const float* __restrict__ x, const int* __restrict__ idx,
                   float* __restrict__ out)
{
    const int t = blockIdx.x * blockDim.x + threadIdx.x;
    if (t >= BATCH * 64) return;
    const int i = t >> 6, j = t & 63;
    out[t] = x[(size_t)idx[i] * 64 + j];
}

extern "C" void kernel_launch(void* const* d_in, const int* in_sizes, int n_in,
                              void* d_out, int out_size, void* d_ws, size_t ws_size,
                              hipStream_t stream)
{
    const int*   pert = (const int*)d_in[0];
    const int*   eidx = (const int*)d_in[1];
    const float* ew   = (const float*)d_in[2];
    const float* emb  = (const float*)d_in[3];
    const float* Wl[4] = {(const float*)d_in[4],  (const float*)d_in[8],
                          (const float*)d_in[12], (const float*)d_in[16]};
    const float* Wr[4] = {(const float*)d_in[5],  (const float*)d_in[9],
                          (const float*)d_in[13], (const float*)d_in[17]};
    const float* av[4] = {(const float*)d_in[6],  (const float*)d_in[10],
                          (const float*)d_in[14], (const float*)d_in[18]};
    const float* bv[4] = {(const float*)d_in[7],  (const float*)d_in[11],
                          (const float*)d_in[15], (const float*)d_in[19]};

    const int N = N_NODES, E = N_EDGES;
    const int* srcp = eidx;
    const int* dstp = eidx + E;

    // workspace layout
    float* ws   = (float*)d_ws;
    float* xbuf = ws;                              // N*128 f
    float* xl   = xbuf + (size_t)N * 128;          // N*128 f
    float* xr   = xl   + (size_t)N * 128;          // N*128 f
    int*   deg  = (int*)(xr + (size_t)N * 128);    // N     i
    int*   off  = deg + N;                         // N+1   i
    int*   cur  = off + N + 1;                     // N     i
    int*   ssrc = cur + N;                         // E     i
    float* sew  = (float*)(ssrc + E);              // E     f
    // total ~34 MB

    // ---- build dst-sorted CSR once (graph static across layers)
    hipMemsetAsync(deg, 0, (size_t)N * sizeof(int), stream);
    count_deg_kernel<<<(E + 255) / 256, 256, 0, stream>>>(dstp, deg, E);
    scan_kernel<<<1, 1024, 0, stream>>>(deg, off, cur);
    scatter_kernel<<<(E + 255) / 256, 256, 0, stream>>>(srcp, dstp, ew, cur,
                                                        ssrc, sew, E);

    const float* x = emb;
    for (int layer = 0; layer < 4; ++layer) {
        if (layer == 0)
            transform_kernel<64><<<N / 16, 128, 0, stream>>>(x, Wl[layer], Wr[layer], xl, xr);
        else
            transform_kernel<128><<<N / 16, 128, 0, stream>>>(x, Wl[layer], Wr[layer], xl, xr);

        if (layer < 3)
            gat_node_kernel<0><<<(N * 64 + 255) / 256, 256, 0, stream>>>(
                xl, xr, off, ssrc, sew, av[layer], bv[layer], xbuf);
        else
            gat_node_kernel<1><<<(N * 64 + 255) / 256, 256, 0, stream>>>(
                xl, xr, off, ssrc, sew, av[layer], bv[layer], xbuf);
        x = xbuf;
    }

    gather_kernel<<<(BATCH * 64 + 255) / 256, 256, 0, stream>>>(xbuf, pert, (float*)d_out);
}

// Round 3
// 431.638 us; speedup vs baseline: 2.9360x; 1.2420x over previous
//
#include <hip/hip_runtime.h>
#include <math.h>

#define N_NODES 20000
#define N_EDGES 400000
#define BATCH   4096

// ---- xl = x@Wl, xr = x@Wr  (x: [N][K], W: [K][128], out: [N][128])
// 16 nodes per block, 128 threads (one output column each).
// x rows are block-uniform -> scalar (s_load) path; W is coalesced vector loads.
template<int K>
__global__ __launch_bounds__(128)
void transform_kernel(const float* __restrict__ x,
                      const float* __restrict__ Wl,
                      const float* __restrict__ Wr,
                      float* __restrict__ xl,
                      float* __restrict__ xr)
{
    const int t  = threadIdx.x;      // output column 0..127
    const int n0 = blockIdx.x * 16;
    const float* __restrict__ xb = x + (size_t)n0 * K;

    float accl[16], accr[16];
#pragma unroll
    for (int g = 0; g < 16; ++g) { accl[g] = 0.f; accr[g] = 0.f; }

    for (int k0 = 0; k0 < K; k0 += 4) {
        float wl[4], wr[4];
#pragma unroll
        for (int u = 0; u < 4; ++u) {
            wl[u] = Wl[(k0 + u) * 128 + t];
            wr[u] = Wr[(k0 + u) * 128 + t];
        }
#pragma unroll
        for (int g = 0; g < 16; ++g) {
            const float4 xv = *(const float4*)(xb + g * K + k0);
            accl[g] = fmaf(xv.x, wl[0], accl[g]);
            accr[g] = fmaf(xv.x, wr[0], accr[g]);
            accl[g] = fmaf(xv.y, wl[1], accl[g]);
            accr[g] = fmaf(xv.y, wr[1], accr[g]);
            accl[g] = fmaf(xv.z, wl[2], accl[g]);
            accr[g] = fmaf(xv.z, wr[2], accr[g]);
            accl[g] = fmaf(xv.w, wl[3], accl[g]);
            accr[g] = fmaf(xv.w, wr[3], accr[g]);
        }
    }
#pragma unroll
    for (int g = 0; g < 16; ++g) {
        xl[(size_t)(n0 + g) * 128 + t] = accl[g];
        xr[(size_t)(n0 + g) * 128 + t] = accr[g];
    }
}

// ---- CSR build: count degrees
__global__ __launch_bounds__(256)
void count_deg_kernel(const int* __restrict__ dst, int* __restrict__ deg, int E)
{
    const int e = blockIdx.x * blockDim.x + threadIdx.x;
    if (e < E) atomicAdd(&deg[dst[e]], 1);
}

// ---- exclusive scan over 20000 degrees; one block of 1024 threads
#define CHUNK 20
__global__ __launch_bounds__(1024)
void scan_kernel(const int* __restrict__ deg, int* __restrict__ off,
                 int* __restrict__ cursor)
{
    __shared__ int sums[1024];
    const int t = threadIdx.x;
    const int base = t * CHUNK;
    int local[CHUNK];
    int s = 0;
#pragma unroll
    for (int i = 0; i < CHUNK; ++i) {
        const int idx = base + i;
        local[i] = s;
        s += (idx < N_NODES) ? deg[idx] : 0;
    }
    sums[t] = s;
    __syncthreads();
    for (int d = 1; d < 1024; d <<= 1) {
        int v = (t >= d) ? sums[t - d] : 0;
        __syncthreads();
        sums[t] += v;
        __syncthreads();
    }
    const int prev = (t == 0) ? 0 : sums[t - 1];
#pragma unroll
    for (int i = 0; i < CHUNK; ++i) {
        const int idx = base + i;
        if (idx < N_NODES) {
            const int o = prev + local[i];
            off[idx] = o;
            cursor[idx] = o;
        } else if (idx == N_NODES) {
            off[N_NODES] = prev + local[i];
        }
    }
}

// ---- scatter edges into dst-sorted order
__global__ __launch_bounds__(256)
void scatter_kernel(const int* __restrict__ src, const int* __restrict__ dst,
                    const float* __restrict__ ew, int* __restrict__ cursor,
                    int* __restrict__ ssrc, float* __restrict__ sew, int E)
{
    const int e = blockIdx.x * blockDim.x + threadIdx.x;
    if (e >= E) return;
    const int p = atomicAdd(&cursor[dst[e]], 1);
    ssrc[p] = src[e];
    sew[p]  = ew[e];
}

// ---- fused GATv2 layer: one wave per dst node, online softmax in registers.
// Half-wave per head: lane l<32 owns head0 dims {2l,2l+1}; lanes 32..63 head1.
// Butterfly reduce = 5 within-half shuffles; 1 native exp per lane per edge.
// LAST: nodemap = pert_indices (4096 rows), head-mean, writes d_out directly.
template<int LAST>
__global__ __launch_bounds__(256)
void gat_node_kernel(const float* __restrict__ xl, const float* __restrict__ xr,
                     const int* __restrict__ off, const int* __restrict__ ssrc,
                     const float* __restrict__ sew, const float* __restrict__ a,
                     const float* __restrict__ b, float* __restrict__ xout,
                     const int* __restrict__ nodemap, int nnodes)
{
    const int widx = (int)((blockIdx.x * blockDim.x + threadIdx.x) >> 6);
    if (widx >= nnodes) return;
    const int node = LAST ? nodemap[widx] : widx;
    const int lane = threadIdx.x & 63;
    const int half = lane >> 5;            // head index
    const int hl   = lane & 31;
    const int dbase = half * 64 + 2 * hl;  // column in [0,128)

    const float2 xr2 = *(const float2*)(xr + (size_t)node * 128 + dbase);
    const float2 a2  = *(const float2*)(a + dbase);

    const int e0 = off[node], e1 = off[node + 1];

    float m = -INFINITY, s = 0.f, acc0 = 0.f, acc1 = 0.f;

    for (int e = e0; e < e1; ++e) {
        const int   sn = ssrc[e];
        const float w  = sew[e];
        const float2 xv = *(const float2*)(xl + (size_t)sn * 128 + dbase);

        float v0 = xv.x + xr2.x;
        float v1 = xv.y + xr2.y;
        v0 = v0 >= 0.f ? v0 : 0.2f * v0;
        v1 = v1 >= 0.f ? v1 : 0.2f * v1;
        float p = v0 * a2.x + v1 * a2.y;
#pragma unroll
        for (int o = 16; o > 0; o >>= 1)
            p += __shfl_xor(p, o, 64);     // stays within 32-lane half

        // online softmax: exactly one exp per edge
        const float d   = p - m;           // +inf on first edge
        const float t   = __expf(-fabsf(d));
        const bool  pos = d > 0.f;
        const float r   = pos ? t : 1.f;   // rescale of old state
        const float ex  = pos ? 1.f : t;   // exp(p - m_new)
        m = pos ? p : m;
        const float c = ex * w;
        s    = s * r + ex;
        acc0 = acc0 * r + c * xv.x;
        acc1 = acc1 * r + c * xv.y;
    }

    const float inv = 1.f / (s + 1e-16f);
    const float o0 = acc0 * inv;
    const float o1 = acc1 * inv;

    if (!LAST) {
        float u0 = o0 + b[dbase];
        float u1 = o1 + b[dbase + 1];
        u0 = u0 > 0.f ? u0 : expm1f(u0);
        u1 = u1 > 0.f ? u1 : expm1f(u1);
        *(float2*)(xout + (size_t)node * 128 + dbase) = make_float2(u0, u1);
    } else {
        // mean over heads: bring head1's values to head0's lanes
        const float q0 = __shfl_xor(o0, 32, 64);
        const float q1 = __shfl_xor(o1, 32, 64);
        if (half == 0) {
            const float u0 = 0.5f * (o0 + q0) + b[2 * hl];
            const float u1 = 0.5f * (o1 + q1) + b[2 * hl + 1];
            *(float2*)(xout + (size_t)widx * 64 + 2 * hl) = make_float2(u0, u1);
        }
    }
}

extern "C" void kernel_launch(void* const* d_in, const int* in_sizes, int n_in,
                              void* d_out, int out_size, void* d_ws, size_t ws_size,
                              hipStream_t stream)
{
    const int*   pert = (const int*)d_in[0];
    const int*   eidx = (const int*)d_in[1];
    const float* ew   = (const float*)d_in[2];
    const float* emb  = (const float*)d_in[3];
    const float* Wl[4] = {(const float*)d_in[4],  (const float*)d_in[8],
                          (const float*)d_in[12], (const float*)d_in[16]};
    const float* Wr[4] = {(const float*)d_in[5],  (const float*)d_in[9],
                          (const float*)d_in[13], (const float*)d_in[17]};
    const float* av[4] = {(const float*)d_in[6],  (const float*)d_in[10],
                          (const float*)d_in[14], (const float*)d_in[18]};
    const float* bv[4] = {(const float*)d_in[7],  (const float*)d_in[11],
                          (const float*)d_in[15], (const float*)d_in[19]};

    const int N = N_NODES, E = N_EDGES;
    const int* srcp = eidx;
    const int* dstp = eidx + E;

    // workspace layout
    float* ws   = (float*)d_ws;
    float* xbuf = ws;                              // N*128 f
    float* xl   = xbuf + (size_t)N * 128;          // N*128 f
    float* xr   = xl   + (size_t)N * 128;          // N*128 f
    int*   deg  = (int*)(xr + (size_t)N * 128);    // N     i
    int*   off  = deg + N;                         // N+1   i
    int*   cur  = off + N + 1;                     // N     i
    int*   ssrc = cur + N;                         // E     i
    float* sew  = (float*)(ssrc + E);              // E     f

    // ---- build dst-sorted CSR once (graph static across layers)
    hipMemsetAsync(deg, 0, (size_t)N * sizeof(int), stream);
    count_deg_kernel<<<(E + 255) / 256, 256, 0, stream>>>(dstp, deg, E);
    scan_kernel<<<1, 1024, 0, stream>>>(deg, off, cur);
    scatter_kernel<<<(E + 255) / 256, 256, 0, stream>>>(srcp, dstp, ew, cur,
                                                        ssrc, sew, E);

    const float* x = emb;
    for (int layer = 0; layer < 4; ++layer) {
        if (layer == 0)
            transform_kernel<64><<<N / 16, 128, 0, stream>>>(x, Wl[layer], Wr[layer], xl, xr);
        else
            transform_kernel<128><<<N / 16, 128, 0, stream>>>(x, Wl[layer], Wr[layer], xl, xr);

        if (layer < 3) {
            gat_node_kernel<0><<<(N * 64 + 255) / 256, 256, 0, stream>>>(
                xl, xr, off, ssrc, sew, av[layer], bv[layer], xbuf, nullptr, N);
        } else {
            gat_node_kernel<1><<<(BATCH * 64 + 255) / 256, 256, 0, stream>>>(
                xl, xr, off, ssrc, sew, av[layer], bv[layer], (float*)d_out,
                pert, BATCH);
        }
        x = xbuf;
    }
}

// Round 5
// 330.675 us; speedup vs baseline: 3.8325x; 1.3053x over previous
//
#include <hip/hip_runtime.h>
#include <math.h>

#define N_NODES 20000
#define N_EDGES 400000
#define BATCH   4096

// ---- xl = x@Wl, xr = x@Wr  (x: [N][K], W: [K][128], out: [N][128])
// 16 nodes per block, 128 threads (one output column each).
template<int K>
__global__ __launch_bounds__(128)
void transform_kernel(const float* __restrict__ x,
                      const float* __restrict__ Wl,
                      const float* __restrict__ Wr,
                      float* __restrict__ xl,
                      float* __restrict__ xr)
{
    const int t  = threadIdx.x;      // output column 0..127
    const int n0 = blockIdx.x * 16;
    const float* __restrict__ xb = x + (size_t)n0 * K;

    float accl[16], accr[16];
#pragma unroll
    for (int g = 0; g < 16; ++g) { accl[g] = 0.f; accr[g] = 0.f; }

    for (int k0 = 0; k0 < K; k0 += 4) {
        float wl[4], wr[4];
#pragma unroll
        for (int u = 0; u < 4; ++u) {
            wl[u] = Wl[(k0 + u) * 128 + t];
            wr[u] = Wr[(k0 + u) * 128 + t];
        }
#pragma unroll
        for (int g = 0; g < 16; ++g) {
            const float4 xv = *(const float4*)(xb + g * K + k0);
            accl[g] = fmaf(xv.x, wl[0], accl[g]);
            accr[g] = fmaf(xv.x, wr[0], accr[g]);
            accl[g] = fmaf(xv.y, wl[1], accl[g]);
            accr[g] = fmaf(xv.y, wr[1], accr[g]);
            accl[g] = fmaf(xv.z, wl[2], accl[g]);
            accr[g] = fmaf(xv.z, wr[2], accr[g]);
            accl[g] = fmaf(xv.w, wl[3], accl[g]);
            accr[g] = fmaf(xv.w, wr[3], accr[g]);
        }
    }
#pragma unroll
    for (int g = 0; g < 16; ++g) {
        xl[(size_t)(n0 + g) * 128 + t] = accl[g];
        xr[(size_t)(n0 + g) * 128 + t] = accr[g];
    }
}

// ---- CSR build: count degrees
__global__ __launch_bounds__(256)
void count_deg_kernel(const int* __restrict__ dst, int* __restrict__ deg, int E)
{
    const int e = blockIdx.x * blockDim.x + threadIdx.x;
    if (e < E) atomicAdd(&deg[dst[e]], 1);
}

// ---- exclusive scan over 20000 degrees; one block, LDS-staged coalesced I/O.
// xs padded to 1024*CHUNK with zeroed tail (round-4 crash: unpadded overrun).
#define CHUNK 20
#define SCAN_PAD (1024 * CHUNK)
__global__ __launch_bounds__(1024)
void scan_kernel(const int* __restrict__ deg, int* __restrict__ off,
                 int* __restrict__ cursor)
{
    __shared__ int xs[SCAN_PAD];    // 80 KB (+ pad)
    __shared__ int sums[1024];
    const int t = threadIdx.x;
    for (int i = t; i < SCAN_PAD; i += 1024)
        xs[i] = (i < N_NODES) ? deg[i] : 0;
    __syncthreads();

    const int base = t * CHUNK;
    int local[CHUNK];
    int s = 0;
#pragma unroll
    for (int i = 0; i < CHUNK; ++i) {
        local[i] = s;
        s += xs[base + i];
    }
    sums[t] = s;
    __syncthreads();
    for (int d = 1; d < 1024; d <<= 1) {
        int v = (t >= d) ? sums[t - d] : 0;
        __syncthreads();
        sums[t] += v;
        __syncthreads();
    }
    const int prev = (t == 0) ? 0 : sums[t - 1];
#pragma unroll
    for (int i = 0; i < CHUNK; ++i)
        xs[base + i] = prev + local[i];
    __syncthreads();
    for (int i = t; i < N_NODES; i += 1024) {
        const int o = xs[i];
        off[i] = o;
        cursor[i] = o;
    }
    if (t == 1023) off[N_NODES] = sums[1023];
}

// ---- scatter edges into dst-sorted order
__global__ __launch_bounds__(256)
void scatter_kernel(const int* __restrict__ src, const int* __restrict__ dst,
                    const float* __restrict__ ew, int* __restrict__ cursor,
                    int* __restrict__ ssrc, float* __restrict__ sew, int E)
{
    const int e = blockIdx.x * blockDim.x + threadIdx.x;
    if (e >= E) return;
    const int p = atomicAdd(&cursor[dst[e]], 1);
    ssrc[p] = src[e];
    sew[p]  = ew[e];
}

// ---- fused GATv2 layer: one wave per dst node, 4 edge slots in parallel.
// lane = q*16 + h*8 + j : q = edge slot (4), h = head (2), j = dim chunk (8 dims).
// Score reduce = 3 shuffles within 8-lane group; 4 independent online-softmax
// states merged at the end (2+2 shuffles for m,s; 16 for acc).
template<int LAST>
__global__ __launch_bounds__(256)
void gat_node_kernel(const float* __restrict__ xl, const float* __restrict__ xr,
                     const int* __restrict__ off, const int* __restrict__ ssrc,
                     const float* __restrict__ sew, const float* __restrict__ a,
                     const float* __restrict__ b, float* __restrict__ xout,
                     const int* __restrict__ nodemap, int nnodes)
{
    const int widx = (int)((blockIdx.x * blockDim.x + threadIdx.x) >> 6);
    if (widx >= nnodes) return;
    const int node = LAST ? nodemap[widx] : widx;
    const int lane = threadIdx.x & 63;
    const int q  = lane >> 4;
    const int h  = (lane >> 3) & 1;
    const int j  = lane & 7;
    const int cb = h * 64 + j * 8;   // column base in [0,128)

    const float4 xrA = *(const float4*)(xr + (size_t)node * 128 + cb);
    const float4 xrB = *(const float4*)(xr + (size_t)node * 128 + cb + 4);
    const float4 aA  = *(const float4*)(a + cb);
    const float4 aB  = *(const float4*)(a + cb + 4);

    const int e0 = off[node], e1 = off[node + 1];

    float m = -1e30f, s = 0.f;
    float acc[8];
#pragma unroll
    for (int k = 0; k < 8; ++k) acc[k] = 0.f;

    for (int ebase = e0; ebase < e1; ebase += 4) {
        const int  ei    = ebase + q;
        const bool valid = ei < e1;
        const int  eic   = valid ? ei : (e1 - 1);
        const int  sn    = ssrc[eic];
        const float w    = valid ? sew[eic] : 0.f;
        const float4 xA = *(const float4*)(xl + (size_t)sn * 128 + cb);
        const float4 xB = *(const float4*)(xl + (size_t)sn * 128 + cb + 4);

        float v0 = xA.x + xrA.x, v1 = xA.y + xrA.y;
        float v2 = xA.z + xrA.z, v3 = xA.w + xrA.w;
        float v4 = xB.x + xrB.x, v5 = xB.y + xrB.y;
        float v6 = xB.z + xrB.z, v7 = xB.w + xrB.w;
        v0 = fmaxf(v0, 0.2f * v0); v1 = fmaxf(v1, 0.2f * v1);
        v2 = fmaxf(v2, 0.2f * v2); v3 = fmaxf(v3, 0.2f * v3);
        v4 = fmaxf(v4, 0.2f * v4); v5 = fmaxf(v5, 0.2f * v5);
        v6 = fmaxf(v6, 0.2f * v6); v7 = fmaxf(v7, 0.2f * v7);
        float t0 = fmaf(v0, aA.x, v1 * aA.y);
        float t1 = fmaf(v2, aA.z, v3 * aA.w);
        float t2 = fmaf(v4, aB.x, v5 * aB.y);
        float t3 = fmaf(v6, aB.z, v7 * aB.w);
        float p = (t0 + t1) + (t2 + t3);
        p += __shfl_xor(p, 1, 64);
        p += __shfl_xor(p, 2, 64);
        p += __shfl_xor(p, 4, 64);
        p = valid ? p : -1e30f;

        // online softmax (one native exp per round per lane)
        const float d   = p - m;
        const float t   = __expf(-fabsf(d));
        const bool  pos = d > 0.f;
        const float r   = pos ? t : 1.f;
        const float ex  = pos ? 1.f : t;
        m = pos ? p : m;
        const float c = ex * w;
        s = s * r + ex;
        acc[0] = acc[0] * r + c * xA.x;
        acc[1] = acc[1] * r + c * xA.y;
        acc[2] = acc[2] * r + c * xA.z;
        acc[3] = acc[3] * r + c * xA.w;
        acc[4] = acc[4] * r + c * xB.x;
        acc[5] = acc[5] * r + c * xB.y;
        acc[6] = acc[6] * r + c * xB.z;
        acc[7] = acc[7] * r + c * xB.w;
    }

    // ---- merge the 4 slot states (across q: lane strides 16, 32)
    float mg = fmaxf(m, __shfl_xor(m, 16, 64));
    mg = fmaxf(mg, __shfl_xor(mg, 32, 64));
    const float rq = __expf(m - mg);        // 0 for dead slots
    float sq = s * rq;
    sq += __shfl_xor(sq, 16, 64);
    sq += __shfl_xor(sq, 32, 64);
#pragma unroll
    for (int k = 0; k < 8; ++k) {
        float v = acc[k] * rq;
        v += __shfl_xor(v, 16, 64);
        v += __shfl_xor(v, 32, 64);
        acc[k] = v;
    }
    const float inv = 1.f / (sq + 1e-16f);

    if (!LAST) {
        if (q == 0) {
            float o[8];
#pragma unroll
            for (int k = 0; k < 8; ++k) {
                float u = acc[k] * inv + b[cb + k];
                o[k] = u > 0.f ? u : expm1f(u);
            }
            *(float4*)(xout + (size_t)node * 128 + cb)     = make_float4(o[0], o[1], o[2], o[3]);
            *(float4*)(xout + (size_t)node * 128 + cb + 4) = make_float4(o[4], o[5], o[6], o[7]);
        }
    } else {
        float o[8];
#pragma unroll
        for (int k = 0; k < 8; ++k) {
            const float v = acc[k] * inv;
            o[k] = 0.5f * (v + __shfl_xor(v, 8, 64)) + b[j * 8 + k];
        }
        if (q == 0 && h == 0) {
            *(float4*)(xout + (size_t)widx * 64 + j * 8)     = make_float4(o[0], o[1], o[2], o[3]);
            *(float4*)(xout + (size_t)widx * 64 + j * 8 + 4) = make_float4(o[4], o[5], o[6], o[7]);
        }
    }
}

extern "C" void kernel_launch(void* const* d_in, const int* in_sizes, int n_in,
                              void* d_out, int out_size, void* d_ws, size_t ws_size,
                              hipStream_t stream)
{
    const int*   pert = (const int*)d_in[0];
    const int*   eidx = (const int*)d_in[1];
    const float* ew   = (const float*)d_in[2];
    const float* emb  = (const float*)d_in[3];
    const float* Wl[4] = {(const float*)d_in[4],  (const float*)d_in[8],
                          (const float*)d_in[12], (const float*)d_in[16]};
    const float* Wr[4] = {(const float*)d_in[5],  (const float*)d_in[9],
                          (const float*)d_in[13], (const float*)d_in[17]};
    const float* av[4] = {(const float*)d_in[6],  (const float*)d_in[10],
                          (const float*)d_in[14], (const float*)d_in[18]};
    const float* bv[4] = {(const float*)d_in[7],  (const float*)d_in[11],
                          (const float*)d_in[15], (const float*)d_in[19]};

    const int N = N_NODES, E = N_EDGES;
    const int* srcp = eidx;
    const int* dstp = eidx + E;

    // workspace layout
    float* ws   = (float*)d_ws;
    float* xbuf = ws;                              // N*128 f
    float* xl   = xbuf + (size_t)N * 128;          // N*128 f
    float* xr   = xl   + (size_t)N * 128;          // N*128 f
    int*   deg  = (int*)(xr + (size_t)N * 128);    // N     i
    int*   off  = deg + N;                         // N+1   i
    int*   cur  = off + N + 1;                     // N     i
    int*   ssrc = cur + N;                         // E     i
    float* sew  = (float*)(ssrc + E);              // E     f

    // ---- build dst-sorted CSR once (graph static across layers)
    hipMemsetAsync(deg, 0, (size_t)N * sizeof(int), stream);
    count_deg_kernel<<<(E + 255) / 256, 256, 0, stream>>>(dstp, deg, E);
    scan_kernel<<<1, 1024, 0, stream>>>(deg, off, cur);
    scatter_kernel<<<(E + 255) / 256, 256, 0, stream>>>(srcp, dstp, ew, cur,
                                                        ssrc, sew, E);

    const float* x = emb;
    for (int layer = 0; layer < 4; ++layer) {
        if (layer == 0)
            transform_kernel<64><<<N / 16, 128, 0, stream>>>(x, Wl[layer], Wr[layer], xl, xr);
        else
            transform_kernel<128><<<N / 16, 128, 0, stream>>>(x, Wl[layer], Wr[layer], xl, xr);

        if (layer < 3) {
            gat_node_kernel<0><<<(N * 64 + 255) / 256, 256, 0, stream>>>(
                xl, xr, off, ssrc, sew, av[layer], bv[layer], xbuf, nullptr, N);
        } else {
            gat_node_kernel<1><<<(BATCH * 64 + 255) / 256, 256, 0, stream>>>(
                xl, xr, off, ssrc, sew, av[layer], bv[layer], (float*)d_out,
                pert, BATCH);
        }
        x = xbuf;
    }
}

// Round 6
// 289.781 us; speedup vs baseline: 4.3733x; 1.1411x over previous
//
#include <hip/hip_runtime.h>
#include <math.h>

#define N_NODES 20000
#define N_EDGES 400000
#define BATCH   4096

// ---- xl = x@Wl, xr = x@Wr  (x: [N][K], W: [K][128], out: [N][128])
// G nodes per block, 128 threads (one output column each).
// G=8 -> 2500 blocks -> ~61% occupancy (G=16 starved the grid: 19%).
template<int K, int G>
__global__ __launch_bounds__(128)
void transform_kernel(const float* __restrict__ x,
                      const float* __restrict__ Wl,
                      const float* __restrict__ Wr,
                      float* __restrict__ xl,
                      float* __restrict__ xr)
{
    const int t  = threadIdx.x;      // output column 0..127
    const int n0 = blockIdx.x * G;
    const float* __restrict__ xb = x + (size_t)n0 * K;

    float accl[G], accr[G];
#pragma unroll
    for (int g = 0; g < G; ++g) { accl[g] = 0.f; accr[g] = 0.f; }

    for (int k0 = 0; k0 < K; k0 += 4) {
        float wl[4], wr[4];
#pragma unroll
        for (int u = 0; u < 4; ++u) {
            wl[u] = Wl[(k0 + u) * 128 + t];
            wr[u] = Wr[(k0 + u) * 128 + t];
        }
#pragma unroll
        for (int g = 0; g < G; ++g) {
            const float4 xv = *(const float4*)(xb + g * K + k0);
            accl[g] = fmaf(xv.x, wl[0], accl[g]);
            accr[g] = fmaf(xv.x, wr[0], accr[g]);
            accl[g] = fmaf(xv.y, wl[1], accl[g]);
            accr[g] = fmaf(xv.y, wr[1], accr[g]);
            accl[g] = fmaf(xv.z, wl[2], accl[g]);
            accr[g] = fmaf(xv.z, wr[2], accr[g]);
            accl[g] = fmaf(xv.w, wl[3], accl[g]);
            accr[g] = fmaf(xv.w, wr[3], accr[g]);
        }
    }
#pragma unroll
    for (int g = 0; g < G; ++g) {
        xl[(size_t)(n0 + g) * 128 + t] = accl[g];
        xr[(size_t)(n0 + g) * 128 + t] = accr[g];
    }
}

// ---- zero an int buffer (replaces runtime fillBuffer, which cost 44 us)
__global__ __launch_bounds__(256)
void zero_kernel(int* __restrict__ p, int n)
{
    const int i = blockIdx.x * blockDim.x + threadIdx.x;
    if (i < n) p[i] = 0;
}

// ---- CSR build: count degrees
__global__ __launch_bounds__(256)
void count_deg_kernel(const int* __restrict__ dst, int* __restrict__ deg, int E)
{
    const int e = blockIdx.x * blockDim.x + threadIdx.x;
    if (e < E) atomicAdd(&deg[dst[e]], 1);
}

// ---- exclusive scan over 20000 degrees; one block, LDS-staged coalesced I/O.
#define CHUNK 20
#define SCAN_PAD (1024 * CHUNK)
__global__ __launch_bounds__(1024)
void scan_kernel(const int* __restrict__ deg, int* __restrict__ off,
                 int* __restrict__ cursor)
{
    __shared__ int xs[SCAN_PAD];    // 80 KB (+ pad)
    __shared__ int sums[1024];
    const int t = threadIdx.x;
    for (int i = t; i < SCAN_PAD; i += 1024)
        xs[i] = (i < N_NODES) ? deg[i] : 0;
    __syncthreads();

    const int base = t * CHUNK;
    int local[CHUNK];
    int s = 0;
#pragma unroll
    for (int i = 0; i < CHUNK; ++i) {
        local[i] = s;
        s += xs[base + i];
    }
    sums[t] = s;
    __syncthreads();
    for (int d = 1; d < 1024; d <<= 1) {
        int v = (t >= d) ? sums[t - d] : 0;
        __syncthreads();
        sums[t] += v;
        __syncthreads();
    }
    const int prev = (t == 0) ? 0 : sums[t - 1];
#pragma unroll
    for (int i = 0; i < CHUNK; ++i)
        xs[base + i] = prev + local[i];
    __syncthreads();
    for (int i = t; i < N_NODES; i += 1024) {
        const int o = xs[i];
        off[i] = o;
        cursor[i] = o;
    }
    if (t == 1023) off[N_NODES] = sums[1023];
}

// ---- scatter edges into dst-sorted order
__global__ __launch_bounds__(256)
void scatter_kernel(const int* __restrict__ src, const int* __restrict__ dst,
                    const float* __restrict__ ew, int* __restrict__ cursor,
                    int* __restrict__ ssrc, float* __restrict__ sew, int E)
{
    const int e = blockIdx.x * blockDim.x + threadIdx.x;
    if (e >= E) return;
    const int p = atomicAdd(&cursor[dst[e]], 1);
    ssrc[p] = src[e];
    sew[p]  = ew[e];
}

// ---- fused GATv2 layer: one wave per dst node, 4 edge slots in parallel.
// lane = q*16 + h*8 + j : q = edge slot (4), h = head (2), j = dim chunk (8 dims).
template<int LAST>
__global__ __launch_bounds__(256)
void gat_node_kernel(const float* __restrict__ xl, const float* __restrict__ xr,
                     const int* __restrict__ off, const int* __restrict__ ssrc,
                     const float* __restrict__ sew, const float* __restrict__ a,
                     const float* __restrict__ b, float* __restrict__ xout,
                     const int* __restrict__ nodemap, int nnodes)
{
    const int widx = (int)((blockIdx.x * blockDim.x + threadIdx.x) >> 6);
    if (widx >= nnodes) return;
    const int node = LAST ? nodemap[widx] : widx;
    const int lane = threadIdx.x & 63;
    const int q  = lane >> 4;
    const int h  = (lane >> 3) & 1;
    const int j  = lane & 7;
    const int cb = h * 64 + j * 8;   // column base in [0,128)

    const float4 xrA = *(const float4*)(xr + (size_t)node * 128 + cb);
    const float4 xrB = *(const float4*)(xr + (size_t)node * 128 + cb + 4);
    const float4 aA  = *(const float4*)(a + cb);
    const float4 aB  = *(const float4*)(a + cb + 4);

    const int e0 = off[node], e1 = off[node + 1];

    float m = -1e30f, s = 0.f;
    float acc[8];
#pragma unroll
    for (int k = 0; k < 8; ++k) acc[k] = 0.f;

    for (int ebase = e0; ebase < e1; ebase += 4) {
        const int  ei    = ebase + q;
        const bool valid = ei < e1;
        const int  eic   = valid ? ei : (e1 - 1);
        const int  sn    = ssrc[eic];
        const float w    = valid ? sew[eic] : 0.f;
        const float4 xA = *(const float4*)(xl + (size_t)sn * 128 + cb);
        const float4 xB = *(const float4*)(xl + (size_t)sn * 128 + cb + 4);

        float v0 = xA.x + xrA.x, v1 = xA.y + xrA.y;
        float v2 = xA.z + xrA.z, v3 = xA.w + xrA.w;
        float v4 = xB.x + xrB.x, v5 = xB.y + xrB.y;
        float v6 = xB.z + xrB.z, v7 = xB.w + xrB.w;
        v0 = fmaxf(v0, 0.2f * v0); v1 = fmaxf(v1, 0.2f * v1);
        v2 = fmaxf(v2, 0.2f * v2); v3 = fmaxf(v3, 0.2f * v3);
        v4 = fmaxf(v4, 0.2f * v4); v5 = fmaxf(v5, 0.2f * v5);
        v6 = fmaxf(v6, 0.2f * v6); v7 = fmaxf(v7, 0.2f * v7);
        float t0 = fmaf(v0, aA.x, v1 * aA.y);
        float t1 = fmaf(v2, aA.z, v3 * aA.w);
        float t2 = fmaf(v4, aB.x, v5 * aB.y);
        float t3 = fmaf(v6, aB.z, v7 * aB.w);
        float p = (t0 + t1) + (t2 + t3);
        p += __shfl_xor(p, 1, 64);
        p += __shfl_xor(p, 2, 64);
        p += __shfl_xor(p, 4, 64);
        p = valid ? p : -1e30f;

        // online softmax (one native exp per round per lane)
        const float d   = p - m;
        const float t   = __expf(-fabsf(d));
        const bool  pos = d > 0.f;
        const float r   = pos ? t : 1.f;
        const float ex  = pos ? 1.f : t;
        m = pos ? p : m;
        const float c = ex * w;
        s = s * r + ex;
        acc[0] = acc[0] * r + c * xA.x;
        acc[1] = acc[1] * r + c * xA.y;
        acc[2] = acc[2] * r + c * xA.z;
        acc[3] = acc[3] * r + c * xA.w;
        acc[4] = acc[4] * r + c * xB.x;
        acc[5] = acc[5] * r + c * xB.y;
        acc[6] = acc[6] * r + c * xB.z;
        acc[7] = acc[7] * r + c * xB.w;
    }

    // ---- merge the 4 slot states (across q: lane strides 16, 32)
    float mg = fmaxf(m, __shfl_xor(m, 16, 64));
    mg = fmaxf(mg, __shfl_xor(mg, 32, 64));
    const float rq = __expf(m - mg);        // 0 for dead slots
    float sq = s * rq;
    sq += __shfl_xor(sq, 16, 64);
    sq += __shfl_xor(sq, 32, 64);
#pragma unroll
    for (int k = 0; k < 8; ++k) {
        float v = acc[k] * rq;
        v += __shfl_xor(v, 16, 64);
        v += __shfl_xor(v, 32, 64);
        acc[k] = v;
    }
    const float inv = 1.f / (sq + 1e-16f);

    if (!LAST) {
        if (q == 0) {
            float o[8];
#pragma unroll
            for (int k = 0; k < 8; ++k) {
                float u = acc[k] * inv + b[cb + k];
                o[k] = u > 0.f ? u : expm1f(u);
            }
            *(float4*)(xout + (size_t)node * 128 + cb)     = make_float4(o[0], o[1], o[2], o[3]);
            *(float4*)(xout + (size_t)node * 128 + cb + 4) = make_float4(o[4], o[5], o[6], o[7]);
        }
    } else {
        float o[8];
#pragma unroll
        for (int k = 0; k < 8; ++k) {
            const float v = acc[k] * inv;
            o[k] = 0.5f * (v + __shfl_xor(v, 8, 64)) + b[j * 8 + k];
        }
        if (q == 0 && h == 0) {
            *(float4*)(xout + (size_t)widx * 64 + j * 8)     = make_float4(o[0], o[1], o[2], o[3]);
            *(float4*)(xout + (size_t)widx * 64 + j * 8 + 4) = make_float4(o[4], o[5], o[6], o[7]);
        }
    }
}

extern "C" void kernel_launch(void* const* d_in, const int* in_sizes, int n_in,
                              void* d_out, int out_size, void* d_ws, size_t ws_size,
                              hipStream_t stream)
{
    const int*   pert = (const int*)d_in[0];
    const int*   eidx = (const int*)d_in[1];
    const float* ew   = (const float*)d_in[2];
    const float* emb  = (const float*)d_in[3];
    const float* Wl[4] = {(const float*)d_in[4],  (const float*)d_in[8],
                          (const float*)d_in[12], (const float*)d_in[16]};
    const float* Wr[4] = {(const float*)d_in[5],  (const float*)d_in[9],
                          (const float*)d_in[13], (const float*)d_in[17]};
    const float* av[4] = {(const float*)d_in[6],  (const float*)d_in[10],
                          (const float*)d_in[14], (const float*)d_in[18]};
    const float* bv[4] = {(const float*)d_in[7],  (const float*)d_in[11],
                          (const float*)d_in[15], (const float*)d_in[19]};

    const int N = N_NODES, E = N_EDGES;
    const int* srcp = eidx;
    const int* dstp = eidx + E;

    // workspace layout
    float* ws   = (float*)d_ws;
    float* xbuf = ws;                              // N*128 f
    float* xl   = xbuf + (size_t)N * 128;          // N*128 f
    float* xr   = xl   + (size_t)N * 128;          // N*128 f
    int*   deg  = (int*)(xr + (size_t)N * 128);    // N     i
    int*   off  = deg + N;                         // N+1   i
    int*   cur  = off + N + 1;                     // N     i
    int*   ssrc = cur + N;                         // E     i
    float* sew  = (float*)(ssrc + E);              // E     f

    // ---- build dst-sorted CSR once (graph static across layers)
    zero_kernel<<<(N + 255) / 256, 256, 0, stream>>>(deg, N);
    count_deg_kernel<<<(E + 255) / 256, 256, 0, stream>>>(dstp, deg, E);
    scan_kernel<<<1, 1024, 0, stream>>>(deg, off, cur);
    scatter_kernel<<<(E + 255) / 256, 256, 0, stream>>>(srcp, dstp, ew, cur,
                                                        ssrc, sew, E);

    const float* x = emb;
    for (int layer = 0; layer < 4; ++layer) {
        if (layer == 0)
            transform_kernel<64, 8><<<N / 8, 128, 0, stream>>>(x, Wl[layer], Wr[layer], xl, xr);
        else
            transform_kernel<128, 8><<<N / 8, 128, 0, stream>>>(x, Wl[layer], Wr[layer], xl, xr);

        if (layer < 3) {
            gat_node_kernel<0><<<(N * 64 + 255) / 256, 256, 0, stream>>>(
                xl, xr, off, ssrc, sew, av[layer], bv[layer], xbuf, nullptr, N);
        } else {
            gat_node_kernel<1><<<(BATCH * 64 + 255) / 256, 256, 0, stream>>>(
                xl, xr, off, ssrc, sew, av[layer], bv[layer], (float*)d_out,
                pert, BATCH);
        }
        x = xbuf;
    }
}